// Round 2
// baseline (563.830 us; speedup 1.0000x reference)
//
#include <hip/hip_runtime.h>
#include <math.h>

#define BN 4
#define LL 4096
#define DM 96
#define DI 192
#define NS 16
#define KK 4
#define RR 6
#define NCH 32
#define LC (LL/NCH)

__device__ __forceinline__ float silu_f(float x){ return x / (1.f + __expf(-x)); }
__device__ __forceinline__ float softplus_f(float x){
  return (x > 20.f) ? x : log1pf(__expf(x));
}

// ---------------- K1: in_proj GEMM: x(B,L,96) @ W^T(384,96) -> xi(B,L,192), zs=silu(z)(B,L,192)
__global__ __launch_bounds__(256) void k1_inproj(const float* __restrict__ x,
    const float* __restrict__ w, float* __restrict__ xi, float* __restrict__ zs)
{
  __shared__ float xt[16][DM];
  __shared__ float wt[64][DM+1];   // +1 pad: conflict-free lane-consecutive-row reads
  int blk = blockIdx.x;
  int b = blk >> 8;
  int l0 = (blk & 255) << 4;
  int tid = threadIdx.x;
  for (int idx = tid; idx < 16*DM; idx += 256) {
    int t = idx / DM, j = idx % DM;
    xt[t][j] = x[((size_t)(b*LL + l0 + t))*DM + j];
  }
  int cl = tid & 63;
  int tb = (tid >> 6) * 4;
  for (int ct = 0; ct < 6; ++ct) {
    int c0 = ct*64;
    __syncthreads();
    for (int idx = tid; idx < 64*DM; idx += 256) {
      int r = idx / DM, j = idx % DM;
      wt[r][j] = w[(c0 + r)*DM + j];
    }
    __syncthreads();
    float acc0=0.f,acc1=0.f,acc2=0.f,acc3=0.f;
    for (int j = 0; j < DM; ++j) {
      float wv = wt[cl][j];
      acc0 += wv * xt[tb+0][j];
      acc1 += wv * xt[tb+1][j];
      acc2 += wv * xt[tb+2][j];
      acc3 += wv * xt[tb+3][j];
    }
    int c = c0 + cl;
    float accs[4] = {acc0,acc1,acc2,acc3};
    #pragma unroll
    for (int tt = 0; tt < 4; ++tt) {
      int l = l0 + tb + tt;
      float v = accs[tt];
      if (c < DI) xi[((size_t)(b*LL + l))*DI + c] = v;
      else        zs[((size_t)(b*LL + l))*DI + (c - DI)] = silu_f(v);
    }
  }
}

// ---------------- K2: depthwise 3x3 conv SAME + bias + SiLU, channel-last.
// U0[b][h*64+w][c], U1[b][w*64+h][c]
__global__ __launch_bounds__(256) void k2_conv(const float* __restrict__ xi,
    const float* __restrict__ cw, const float* __restrict__ cb,
    float* __restrict__ U0, float* __restrict__ U1)
{
  int n = blockIdx.x*256 + threadIdx.x;
  if (n >= BN*LL*DI) return;
  int c  = n % DI;
  int w_ = (n / DI) & 63;
  int h_ = (n / (DI*64)) & 63;
  int b  = n / (DI*LL);
  float acc = cb[c];
  #pragma unroll
  for (int kh = 0; kh < 3; ++kh) {
    int hh = h_ + kh - 1;
    if (hh < 0 || hh >= 64) continue;
    #pragma unroll
    for (int kw = 0; kw < 3; ++kw) {
      int ww2 = w_ + kw - 1;
      if (ww2 < 0 || ww2 >= 64) continue;
      acc += xi[((size_t)(b*LL) + hh*64 + ww2)*DI + c] * cw[c*9 + kh*3 + kw];
    }
  }
  float v = silu_f(acc);
  U0[((size_t)(b*LL) + h_*64 + w_)*DI + c] = v;
  U1[((size_t)(b*LL) + w_*64 + h_)*DI + c] = v;
}

// ---------------- K3: x_proj (38x192) + dt_proj (192x6) + softplus
// delta(B,K,L,192), BCs(B,K,L,32) [B:0..15, C:16..31]
__global__ __launch_bounds__(256) void k3_xproj(const float* __restrict__ U0,
    const float* __restrict__ U1, const float* __restrict__ xw,
    const float* __restrict__ dtw, const float* __restrict__ dtb,
    float* __restrict__ dlt, float* __restrict__ BCs)
{
  __shared__ float ut[16][DI];
  __shared__ float xwS[38][DI+3];   // pad 195 (odd-ish stride) for bank spread
  __shared__ float c38S[16][38];
  int blk = blockIdx.x;
  int tile = blk & 255; int k = (blk >> 8) & 3; int b = blk >> 10;
  int l0 = tile << 4;
  int tid = threadIdx.x;
  const float* U = (k & 1) ? U1 : U0;
  for (int idx = tid; idx < 16*DI; idx += 256) {
    int t = idx / DI, j = idx % DI;
    ut[t][j] = U[((size_t)(b*LL + l0 + t))*DI + j];
  }
  for (int idx = tid; idx < 38*DI; idx += 256) {
    int r = idx / DI, j = idx % DI;
    xwS[r][j] = xw[(k*38 + r)*DI + j];
  }
  __syncthreads();
  for (int idx = tid; idx < 16*38; idx += 256) {
    int t = idx / 38, cc = idx % 38;
    float acc = 0.f;
    for (int j = 0; j < DI; ++j) acc += ut[t][j] * xwS[cc][j];
    c38S[t][cc] = acc;
    if (cc >= RR) BCs[(((size_t)(b*KK + k)*LL) + l0 + t)*32 + (cc - RR)] = acc;
  }
  __syncthreads();
  for (int idx = tid; idx < 16*DI; idx += 256) {
    int t = idx / DI, d = idx % DI;
    float acc = dtb[k*DI + d];
    #pragma unroll
    for (int r = 0; r < RR; ++r) acc += c38S[t][r] * dtw[(k*DI + d)*RR + r];
    dlt[(((size_t)(b*KK + k)*LL) + l0 + t)*DI + d] = softplus_f(acc);
  }
}

// ---------------- K4a: scan pass 1 — per-chunk local scan -> hend, sum(delta)
__global__ __launch_bounds__(192) void k4a_pass1(const float* __restrict__ dlt,
    const float* __restrict__ U0, const float* __restrict__ U1,
    const float* __restrict__ BCs, const float* __restrict__ A_logs,
    float* __restrict__ hend, float* __restrict__ Ssum)
{
  int blk = blockIdx.x;
  int c = blk % NCH; int k = (blk / NCH) & 3; int b = blk / (NCH*4);
  int d = threadIdx.x;
  const float* U = (k & 1) ? U1 : U0;
  int b4k = b*KK + k;
  float an[NS];
  #pragma unroll
  for (int n = 0; n < NS; ++n) an[n] = -__expf(A_logs[(k*DI + d)*NS + n]);
  float a0 = an[0];
  bool chain = true;
  #pragma unroll
  for (int n = 1; n < NS; ++n)
    chain = chain && (fabsf(an[n] - a0*(float)(n+1)) <= 1e-3f*(float)(n+1));
  float h[NS];
  #pragma unroll
  for (int n = 0; n < NS; ++n) h[n] = 0.f;
  float sd = 0.f;
  bool fwd = (k < 2);
  int lo = c * LC;
  for (int s = 0; s < LC; ++s) {
    int l = fwd ? (lo + s) : (lo + LC - 1 - s);
    float dv = dlt[((size_t)b4k*LL + l)*DI + d];
    float u  = U[((size_t)(b*LL) + l)*DI + d];
    float du = dv * u;
    sd += dv;
    const float4* bc = (const float4*)(BCs + ((size_t)b4k*LL + l)*32);
    float4 B0 = bc[0], B1 = bc[1], B2 = bc[2], B3 = bc[3];
    float Bv[NS] = {B0.x,B0.y,B0.z,B0.w, B1.x,B1.y,B1.z,B1.w,
                    B2.x,B2.y,B2.z,B2.w, B3.x,B3.y,B3.z,B3.w};
    if (chain) {
      float e1 = __expf(a0 * dv);
      float p = 1.f;
      #pragma unroll
      for (int n = 0; n < NS; ++n) { p *= e1; h[n] = p*h[n] + du*Bv[n]; }
    } else {
      #pragma unroll
      for (int n = 0; n < NS; ++n) { float dA = __expf(an[n]*dv); h[n] = dA*h[n] + du*Bv[n]; }
    }
  }
  size_t base = ((size_t)b4k*NCH + c)*DI + d;
  float4* he = (float4*)(hend + base*NS);
  he[0] = make_float4(h[0], h[1], h[2], h[3]);
  he[1] = make_float4(h[4], h[5], h[6], h[7]);
  he[2] = make_float4(h[8], h[9], h[10],h[11]);
  he[3] = make_float4(h[12],h[13],h[14],h[15]);
  Ssum[base] = sd;
}

// ---------------- K4b: combine — prefix chunk states (scan-time order) -> hin
__global__ __launch_bounds__(256) void k4b_combine(const float* __restrict__ hend,
    const float* __restrict__ Ssum, const float* __restrict__ A_logs,
    float* __restrict__ hin)
{
  int blk = blockIdx.x;
  int dgrp = blk % 12; int k = (blk/12) & 3; int b = blk/48;
  int tid = threadIdx.x;
  int d = dgrp*16 + (tid >> 4);
  int n = tid & 15;
  int b4k = b*KK + k;
  float an = -__expf(A_logs[(k*DI + d)*NS + n]);
  bool fwd = (k < 2);
  float h = 0.f;
  for (int s = 0; s < NCH; ++s) {
    int c = fwd ? s : (NCH - 1 - s);
    size_t base = ((size_t)b4k*NCH + c)*DI + d;
    hin[base*NS + n] = h;
    h = __expf(an * Ssum[base]) * h + hend[base*NS + n];
  }
}

// ---------------- K4c: scan pass 2 — full scan from hin, emit y (atomic merge)
__global__ __launch_bounds__(192) void k4c_pass2(const float* __restrict__ dlt,
    const float* __restrict__ U0, const float* __restrict__ U1,
    const float* __restrict__ BCs, const float* __restrict__ A_logs,
    const float* __restrict__ Dsv, const float* __restrict__ hin,
    float* __restrict__ ytot)
{
  int blk = blockIdx.x;
  int c = blk % NCH; int k = (blk / NCH) & 3; int b = blk / (NCH*4);
  int d = threadIdx.x;
  const float* U = (k & 1) ? U1 : U0;
  int b4k = b*KK + k;
  float an[NS];
  #pragma unroll
  for (int n = 0; n < NS; ++n) an[n] = -__expf(A_logs[(k*DI + d)*NS + n]);
  float a0 = an[0];
  bool chain = true;
  #pragma unroll
  for (int n = 1; n < NS; ++n)
    chain = chain && (fabsf(an[n] - a0*(float)(n+1)) <= 1e-3f*(float)(n+1));
  float Dd = Dsv[k*DI + d];
  size_t base = ((size_t)b4k*NCH + c)*DI + d;
  float h[NS];
  {
    const float4* hi = (const float4*)(hin + base*NS);
    float4 h0 = hi[0], h1 = hi[1], h2 = hi[2], h3 = hi[3];
    h[0]=h0.x; h[1]=h0.y; h[2]=h0.z; h[3]=h0.w;
    h[4]=h1.x; h[5]=h1.y; h[6]=h1.z; h[7]=h1.w;
    h[8]=h2.x; h[9]=h2.y; h[10]=h2.z; h[11]=h2.w;
    h[12]=h3.x; h[13]=h3.y; h[14]=h3.z; h[15]=h3.w;
  }
  bool fwd = (k < 2);
  int lo = c * LC;
  for (int s = 0; s < LC; ++s) {
    int l = fwd ? (lo + s) : (lo + LC - 1 - s);
    float dv = dlt[((size_t)b4k*LL + l)*DI + d];
    float u  = U[((size_t)(b*LL) + l)*DI + d];
    float du = dv * u;
    const float4* bc = (const float4*)(BCs + ((size_t)b4k*LL + l)*32);
    float4 B0 = bc[0], B1 = bc[1], B2 = bc[2], B3 = bc[3];
    float4 C0 = bc[4], C1 = bc[5], C2 = bc[6], C3 = bc[7];
    float Bv[NS] = {B0.x,B0.y,B0.z,B0.w, B1.x,B1.y,B1.z,B1.w,
                    B2.x,B2.y,B2.z,B2.w, B3.x,B3.y,B3.z,B3.w};
    float Cv[NS] = {C0.x,C0.y,C0.z,C0.w, C1.x,C1.y,C1.z,C1.w,
                    C2.x,C2.y,C2.z,C2.w, C3.x,C3.y,C3.z,C3.w};
    if (chain) {
      float e1 = __expf(a0 * dv);
      float p = 1.f;
      #pragma unroll
      for (int n = 0; n < NS; ++n) { p *= e1; h[n] = p*h[n] + du*Bv[n]; }
    } else {
      #pragma unroll
      for (int n = 0; n < NS; ++n) { float dA = __expf(an[n]*dv); h[n] = dA*h[n] + du*Bv[n]; }
    }
    float acc = Dd * u;
    #pragma unroll
    for (int n = 0; n < NS; ++n) acc += h[n]*Cv[n];
    int pos = (k & 1) ? (((l & 63) << 6) | (l >> 6)) : l;
    unsafeAtomicAdd(&ytot[((size_t)(b*LL) + pos)*DI + d], acc);
  }
}

// ---------------- K5: LayerNorm + silu(z) gate + out_proj
__global__ __launch_bounds__(256) void k5_final(const float* __restrict__ ytot,
    const float* __restrict__ zs, const float* __restrict__ g,
    const float* __restrict__ bb, const float* __restrict__ ow,
    float* __restrict__ out)
{
  __shared__ float yt[16][DI+8];
  __shared__ float muS[16], rsS[16];
  int blk = blockIdx.x;
  int b = blk >> 8; int l0 = (blk & 255) << 4;
  int tid = threadIdx.x;
  for (int idx = tid; idx < 16*DI; idx += 256) {
    int t = idx / DI, dd2 = idx % DI;
    yt[t][dd2] = ytot[((size_t)(b*LL) + l0 + t)*DI + dd2];
  }
  __syncthreads();
  {
    int t = tid >> 4, jj = tid & 15;
    float s1 = 0.f, s2 = 0.f;
    #pragma unroll
    for (int i = 0; i < 12; ++i) {
      float v = yt[t][jj*12 + i];
      s1 += v; s2 += v*v;
    }
    #pragma unroll
    for (int m = 1; m < 16; m <<= 1) {
      s1 += __shfl_xor(s1, m);
      s2 += __shfl_xor(s2, m);
    }
    if (jj == 0) {
      float mu = s1 / (float)DI;
      float var = s2 / (float)DI - mu*mu;
      muS[t] = mu;
      rsS[t] = rsqrtf(var + 1e-5f);
    }
  }
  __syncthreads();
  for (int idx = tid; idx < 16*DI; idx += 256) {
    int t = idx / DI, dd2 = idx % DI;
    float v = (yt[t][dd2] - muS[t]) * rsS[t] * g[dd2] + bb[dd2];
    v *= zs[((size_t)(b*LL) + l0 + t)*DI + dd2];
    yt[t][dd2] = v;
  }
  __syncthreads();
  for (int idx = tid; idx < 16*DM; idx += 256) {
    int t = idx / DM, cc = idx % DM;
    float acc = 0.f;
    for (int j = 0; j < DI; ++j) acc += yt[t][j] * ow[cc*DI + j];
    out[((size_t)(b*LL) + l0 + t)*DM + cc] = acc;
  }
}

extern "C" void kernel_launch(void* const* d_in, const int* in_sizes, int n_in,
                              void* d_out, int out_size, void* d_ws, size_t ws_size,
                              hipStream_t stream)
{
  const float* x    = (const float*)d_in[0];
  const float* ipw  = (const float*)d_in[1];
  const float* cw   = (const float*)d_in[2];
  const float* cb   = (const float*)d_in[3];
  const float* xpw  = (const float*)d_in[4];
  const float* dtwp = (const float*)d_in[5];
  const float* dtbp = (const float*)d_in[6];
  const float* alog = (const float*)d_in[7];
  const float* dsp  = (const float*)d_in[8];
  const float* ng   = (const float*)d_in[9];
  const float* nbp  = (const float*)d_in[10];
  const float* owp  = (const float*)d_in[11];
  float* out = (float*)d_out;

  float* ws = (float*)d_ws;
  size_t off = 0;
  float* ytot = ws + off; off += (size_t)BN*LL*DI;
  float* zs   = ws + off; off += (size_t)BN*LL*DI;
  float* xi   = ws + off; off += (size_t)BN*LL*DI;
  float* U0   = ws + off; off += (size_t)BN*LL*DI;
  float* U1   = ws + off; off += (size_t)BN*LL*DI;
  float* dlt  = ws + off; off += (size_t)BN*KK*LL*DI;
  float* BCs  = ws + off; off += (size_t)BN*KK*LL*32;
  float* hend = ws + off; off += (size_t)BN*KK*NCH*DI*NS;
  float* Ssum = ws + off; off += (size_t)BN*KK*NCH*DI;
  float* hin  = ws + off; off += (size_t)BN*KK*NCH*DI*NS;
  (void)ws_size; (void)in_sizes; (void)n_in; (void)out_size;

  hipMemsetAsync(ytot, 0, (size_t)BN*LL*DI*sizeof(float), stream);
  k1_inproj<<<dim3(BN*256), dim3(256), 0, stream>>>(x, ipw, xi, zs);
  k2_conv<<<dim3((BN*LL*DI)/256), dim3(256), 0, stream>>>(xi, cw, cb, U0, U1);
  k3_xproj<<<dim3(BN*KK*256), dim3(256), 0, stream>>>(U0, U1, xpw, dtwp, dtbp, dlt, BCs);
  k4a_pass1<<<dim3(BN*KK*NCH), dim3(192), 0, stream>>>(dlt, U0, U1, BCs, alog, hend, Ssum);
  k4b_combine<<<dim3(BN*KK*12), dim3(256), 0, stream>>>(hend, Ssum, alog, hin);
  k4c_pass2<<<dim3(BN*KK*NCH), dim3(192), 0, stream>>>(dlt, U0, U1, BCs, alog, dsp, hin, ytot);
  k5_final<<<dim3(BN*256), dim3(256), 0, stream>>>(ytot, zs, ng, nbp, owp, out);
}

// Round 3
// 405.523 us; speedup vs baseline: 1.3904x; 1.3904x over previous
//
#include <hip/hip_runtime.h>
#include <math.h>

#define BN 4
#define LL 4096
#define DM 96
#define DI 192
#define NS 16
#define KK 4
#define RR 6
#define NCH 64
#define LC (LL/NCH)

__device__ __forceinline__ float silu_f(float x){ return x / (1.f + __expf(-x)); }
__device__ __forceinline__ float softplus_f(float x){
  return (x > 20.f) ? x : log1pf(__expf(x));
}
__device__ __forceinline__ void fma4(float4& a, const float4 w, const float4 v){
  a.x = fmaf(w.x, v.x, a.x); a.y = fmaf(w.y, v.y, a.y);
  a.z = fmaf(w.z, v.z, a.z); a.w = fmaf(w.w, v.w, a.w);
}

// ---------------- K1: in_proj GEMM: x(B,L,96) @ W^T(384,96) -> xi(B,L,192), zs=silu(z)
__global__ __launch_bounds__(256) void k1_inproj(const float* __restrict__ x,
    const float* __restrict__ w, float* __restrict__ xi, float* __restrict__ zs)
{
  __shared__ float xt[16][DM];        // 96 floats/row, f4-aligned
  __shared__ float wt[64][DM+4];      // stride 100 floats (f4-aligned, bank-spread)
  int blk = blockIdx.x;
  int b = blk >> 8;
  int l0 = (blk & 255) << 4;
  int tid = threadIdx.x;
  for (int idx = tid; idx < 16*24; idx += 256) {
    int t = idx / 24, jj = idx % 24;
    ((float4*)xt[t])[jj] = *(const float4*)(x + ((size_t)(b*LL + l0 + t))*DM + 4*jj);
  }
  int cl = tid & 63;
  int tb = (tid >> 6) * 4;            // wave-uniform -> xt reads broadcast
  for (int ct = 0; ct < 6; ++ct) {
    int c0 = ct*64;
    __syncthreads();
    for (int idx = tid; idx < 64*24; idx += 256) {
      int r = idx / 24, jj = idx % 24;
      ((float4*)wt[r])[jj] = *(const float4*)(w + (size_t)(c0 + r)*DM + 4*jj);
    }
    __syncthreads();
    float4 a0={0,0,0,0}, a1={0,0,0,0}, a2={0,0,0,0}, a3={0,0,0,0};
    const float4* wr = (const float4*)wt[cl];
    const float4* x0 = (const float4*)xt[tb+0];
    const float4* x1 = (const float4*)xt[tb+1];
    const float4* x2 = (const float4*)xt[tb+2];
    const float4* x3 = (const float4*)xt[tb+3];
    #pragma unroll
    for (int jj = 0; jj < 24; ++jj) {
      float4 w4 = wr[jj];
      fma4(a0, w4, x0[jj]); fma4(a1, w4, x1[jj]);
      fma4(a2, w4, x2[jj]); fma4(a3, w4, x3[jj]);
    }
    float accs[4] = { (a0.x+a0.y)+(a0.z+a0.w), (a1.x+a1.y)+(a1.z+a1.w),
                      (a2.x+a2.y)+(a2.z+a2.w), (a3.x+a3.y)+(a3.z+a3.w) };
    int c = c0 + cl;
    #pragma unroll
    for (int tt = 0; tt < 4; ++tt) {
      int l = l0 + tb + tt;
      float v = accs[tt];
      if (c < DI) xi[((size_t)(b*LL + l))*DI + c] = v;
      else        zs[((size_t)(b*LL + l))*DI + (c - DI)] = silu_f(v);
    }
  }
}

// ---------------- K2: depthwise 3x3 conv SAME + bias + SiLU, 4 channels/thread.
__global__ __launch_bounds__(256) void k2_conv(const float* __restrict__ xi,
    const float* __restrict__ cw, const float* __restrict__ cb,
    float* __restrict__ U0, float* __restrict__ U1)
{
  int n = blockIdx.x*256 + threadIdx.x;              // B*L*48 groups
  if (n >= BN*LL*48) return;
  int c4 = n % 48;
  int w_ = (n / 48) & 63;
  int h_ = (n / (48*64)) & 63;
  int b  = n / (48*LL);
  int c  = c4 * 4;
  float4 acc = { cb[c], cb[c+1], cb[c+2], cb[c+3] };
  #pragma unroll
  for (int kh = 0; kh < 3; ++kh) {
    int hh = h_ + kh - 1;
    if (hh < 0 || hh >= 64) continue;
    #pragma unroll
    for (int kw = 0; kw < 3; ++kw) {
      int ww2 = w_ + kw - 1;
      if (ww2 < 0 || ww2 >= 64) continue;
      float4 v = *(const float4*)(xi + ((size_t)(b*LL) + hh*64 + ww2)*DI + c);
      int tap = kh*3 + kw;
      acc.x = fmaf(v.x, cw[(c+0)*9 + tap], acc.x);
      acc.y = fmaf(v.y, cw[(c+1)*9 + tap], acc.y);
      acc.z = fmaf(v.z, cw[(c+2)*9 + tap], acc.z);
      acc.w = fmaf(v.w, cw[(c+3)*9 + tap], acc.w);
    }
  }
  float4 o = { silu_f(acc.x), silu_f(acc.y), silu_f(acc.z), silu_f(acc.w) };
  *(float4*)(U0 + ((size_t)(b*LL) + h_*64 + w_)*DI + c) = o;
  *(float4*)(U1 + ((size_t)(b*LL) + w_*64 + h_)*DI + c) = o;
}

// ---------------- K3: x_proj (38x192) + dt_proj (192x6) + softplus
__global__ __launch_bounds__(256) void k3_xproj(const float* __restrict__ U0,
    const float* __restrict__ U1, const float* __restrict__ xw,
    const float* __restrict__ dtw, const float* __restrict__ dtb,
    float* __restrict__ dlt, float* __restrict__ BCs)
{
  __shared__ float ut[16][DI];
  __shared__ float xwS[38][DI+4];     // stride 196 floats, f4-aligned
  __shared__ float c38S[16][38];
  __shared__ float dtwS[DI*RR];
  int blk = blockIdx.x;
  int tile = blk & 255; int k = (blk >> 8) & 3; int b = blk >> 10;
  int l0 = tile << 4;
  int tid = threadIdx.x;
  const float* U = (k & 1) ? U1 : U0;
  for (int idx = tid; idx < 16*48; idx += 256) {
    int t = idx / 48, jj = idx % 48;
    ((float4*)ut[t])[jj] = *(const float4*)(U + ((size_t)(b*LL + l0 + t))*DI + 4*jj);
  }
  for (int idx = tid; idx < 38*48; idx += 256) {
    int r = idx / 48, jj = idx % 48;
    ((float4*)xwS[r])[jj] = *(const float4*)(xw + (size_t)(k*38 + r)*DI + 4*jj);
  }
  for (int idx = tid; idx < DI*RR; idx += 256)
    dtwS[idx] = dtw[k*DI*RR + idx];
  __syncthreads();
  for (int idx = tid; idx < 16*38; idx += 256) {
    int t = idx / 38, cc = idx % 38;
    const float4* u4 = (const float4*)ut[t];
    const float4* w4 = (const float4*)xwS[cc];
    float4 a4 = {0,0,0,0};
    #pragma unroll
    for (int jj = 0; jj < 48; ++jj) fma4(a4, u4[jj], w4[jj]);
    float acc = (a4.x+a4.y)+(a4.z+a4.w);
    c38S[t][cc] = acc;
    if (cc >= RR) BCs[(((size_t)(b*KK + k)*LL) + l0 + t)*32 + (cc - RR)] = acc;
  }
  __syncthreads();
  for (int idx = tid; idx < 16*DI; idx += 256) {
    int t = idx / DI, d = idx % DI;
    float acc = dtb[k*DI + d];
    #pragma unroll
    for (int r = 0; r < RR; ++r) acc += c38S[t][r] * dtwS[d*RR + r];
    dlt[(((size_t)(b*KK + k)*LL) + l0 + t)*DI + d] = softplus_f(acc);
  }
}

// ---- exp-power tree: ep[n] = e1^(n+1), log depth, independent-ish muls
__device__ __forceinline__ void pow_tree(float e1, float* ep){
  ep[0]=e1;
  ep[1]=e1*e1;
  ep[2]=ep[1]*e1;  ep[3]=ep[1]*ep[1];
  ep[4]=ep[3]*e1;  ep[5]=ep[3]*ep[1]; ep[6]=ep[3]*ep[2]; ep[7]=ep[3]*ep[3];
  #pragma unroll
  for (int i=0;i<8;++i) ep[8+i]=ep[7]*ep[i];
}

// ---------------- K4a: scan pass 1 — per-chunk local scan -> hend, sum(delta)
__global__ __launch_bounds__(192) void k4a_pass1(const float* __restrict__ dlt,
    const float* __restrict__ U0, const float* __restrict__ U1,
    const float* __restrict__ BCs, const float* __restrict__ A_logs,
    float* __restrict__ hst, float* __restrict__ Ssum)
{
  int blk = blockIdx.x;
  int c = blk % NCH; int k = (blk / NCH) & 3; int b = blk / (NCH*4);
  int d = threadIdx.x;
  const float* U = (k & 1) ? U1 : U0;
  int b4k = b*KK + k;
  float an[NS];
  #pragma unroll
  for (int n = 0; n < NS; ++n) an[n] = -__expf(A_logs[(k*DI + d)*NS + n]);
  float a0 = an[0];
  bool chain = true;
  #pragma unroll
  for (int n = 1; n < NS; ++n)
    chain = chain && (fabsf(an[n] - a0*(float)(n+1)) <= 1e-3f*(float)(n+1));
  float h[NS];
  #pragma unroll
  for (int n = 0; n < NS; ++n) h[n] = 0.f;
  float sd = 0.f;
  bool fwd = (k < 2);
  int lo = c * LC;
  int dir = fwd ? 1 : -1;
  int l = fwd ? lo : (lo + LC - 1);
  const float* pd = dlt + ((size_t)b4k*LL + l)*DI + d;
  const float* pu = U + ((size_t)(b*LL) + l)*DI + d;
  const float4* pbc = (const float4*)(BCs + ((size_t)b4k*LL + l)*32);
  intptr_t pinc = (intptr_t)dir * DI;
  intptr_t bcinc = (intptr_t)dir * 8;
  #pragma unroll 2
  for (int s = 0; s < LC; ++s) {
    float dv = *pd;
    float u  = *pu;
    float du = dv * u;
    sd += dv;
    float4 B0 = pbc[0], B1 = pbc[1], B2 = pbc[2], B3 = pbc[3];
    float Bv[NS] = {B0.x,B0.y,B0.z,B0.w, B1.x,B1.y,B1.z,B1.w,
                    B2.x,B2.y,B2.z,B2.w, B3.x,B3.y,B3.z,B3.w};
    if (chain) {
      float ep[NS];
      pow_tree(__expf(a0 * dv), ep);
      #pragma unroll
      for (int n = 0; n < NS; ++n) h[n] = fmaf(ep[n], h[n], du*Bv[n]);
    } else {
      #pragma unroll
      for (int n = 0; n < NS; ++n) h[n] = fmaf(__expf(an[n]*dv), h[n], du*Bv[n]);
    }
    pd += pinc; pu += pinc; pbc += bcinc;
  }
  size_t base = ((size_t)b4k*NCH + c)*DI + d;
  float4* he = (float4*)(hst + base*NS);
  he[0] = make_float4(h[0], h[1], h[2], h[3]);
  he[1] = make_float4(h[4], h[5], h[6], h[7]);
  he[2] = make_float4(h[8], h[9], h[10],h[11]);
  he[3] = make_float4(h[12],h[13],h[14],h[15]);
  Ssum[base] = sd;
}

// ---------------- K4b: combine — prefix chunk states in place (hend -> hin)
__global__ __launch_bounds__(256) void k4b_combine(float* __restrict__ hst,
    const float* __restrict__ Ssum, const float* __restrict__ A_logs)
{
  int blk = blockIdx.x;
  int dgrp = blk % 12; int k = (blk/12) & 3; int b = blk/48;
  int tid = threadIdx.x;
  int d = dgrp*16 + (tid >> 4);
  int n = tid & 15;
  int b4k = b*KK + k;
  float an = -__expf(A_logs[(k*DI + d)*NS + n]);
  bool fwd = (k < 2);
  float h = 0.f;
  for (int s = 0; s < NCH; ++s) {
    int c = fwd ? s : (NCH - 1 - s);
    size_t base = ((size_t)b4k*NCH + c)*DI + d;
    float he = hst[base*NS + n];
    hst[base*NS + n] = h;          // now holds h_in for this chunk
    h = __expf(an * Ssum[base]) * h + he;
  }
}

// ---------------- K4c: scan pass 2 — full scan from hin, emit y (atomic merge)
__global__ __launch_bounds__(192) void k4c_pass2(const float* __restrict__ dlt,
    const float* __restrict__ U0, const float* __restrict__ U1,
    const float* __restrict__ BCs, const float* __restrict__ A_logs,
    const float* __restrict__ Dsv, const float* __restrict__ hst,
    float* __restrict__ ytot)
{
  int blk = blockIdx.x;
  int c = blk % NCH; int k = (blk / NCH) & 3; int b = blk / (NCH*4);
  int d = threadIdx.x;
  const float* U = (k & 1) ? U1 : U0;
  int b4k = b*KK + k;
  float an[NS];
  #pragma unroll
  for (int n = 0; n < NS; ++n) an[n] = -__expf(A_logs[(k*DI + d)*NS + n]);
  float a0 = an[0];
  bool chain = true;
  #pragma unroll
  for (int n = 1; n < NS; ++n)
    chain = chain && (fabsf(an[n] - a0*(float)(n+1)) <= 1e-3f*(float)(n+1));
  float Dd = Dsv[k*DI + d];
  size_t base = ((size_t)b4k*NCH + c)*DI + d;
  float h[NS];
  {
    const float4* hi = (const float4*)(hst + base*NS);
    float4 h0 = hi[0], h1 = hi[1], h2 = hi[2], h3 = hi[3];
    h[0]=h0.x; h[1]=h0.y; h[2]=h0.z; h[3]=h0.w;
    h[4]=h1.x; h[5]=h1.y; h[6]=h1.z; h[7]=h1.w;
    h[8]=h2.x; h[9]=h2.y; h[10]=h2.z; h[11]=h2.w;
    h[12]=h3.x; h[13]=h3.y; h[14]=h3.z; h[15]=h3.w;
  }
  bool fwd = (k < 2);
  int lo = c * LC;
  int dir = fwd ? 1 : -1;
  int l = fwd ? lo : (lo + LC - 1);
  const float* pd = dlt + ((size_t)b4k*LL + l)*DI + d;
  const float* pu = U + ((size_t)(b*LL) + l)*DI + d;
  const float4* pbc = (const float4*)(BCs + ((size_t)b4k*LL + l)*32);
  intptr_t pinc = (intptr_t)dir * DI;
  intptr_t bcinc = (intptr_t)dir * 8;
  bool odd = (k & 1);
  #pragma unroll 2
  for (int s = 0; s < LC; ++s) {
    float dv = *pd;
    float u  = *pu;
    float du = dv * u;
    float4 B0 = pbc[0], B1 = pbc[1], B2 = pbc[2], B3 = pbc[3];
    float4 C0 = pbc[4], C1 = pbc[5], C2 = pbc[6], C3 = pbc[7];
    float Bv[NS] = {B0.x,B0.y,B0.z,B0.w, B1.x,B1.y,B1.z,B1.w,
                    B2.x,B2.y,B2.z,B2.w, B3.x,B3.y,B3.z,B3.w};
    float Cv[NS] = {C0.x,C0.y,C0.z,C0.w, C1.x,C1.y,C1.z,C1.w,
                    C2.x,C2.y,C2.z,C2.w, C3.x,C3.y,C3.z,C3.w};
    if (chain) {
      float ep[NS];
      pow_tree(__expf(a0 * dv), ep);
      #pragma unroll
      for (int n = 0; n < NS; ++n) h[n] = fmaf(ep[n], h[n], du*Bv[n]);
    } else {
      #pragma unroll
      for (int n = 0; n < NS; ++n) h[n] = fmaf(__expf(an[n]*dv), h[n], du*Bv[n]);
    }
    float p0 = Dd*u, p1 = 0.f, p2 = 0.f, p3 = 0.f;
    #pragma unroll
    for (int n = 0; n < NS; n += 4) {
      p0 = fmaf(h[n+0], Cv[n+0], p0);
      p1 = fmaf(h[n+1], Cv[n+1], p1);
      p2 = fmaf(h[n+2], Cv[n+2], p2);
      p3 = fmaf(h[n+3], Cv[n+3], p3);
    }
    int pos = odd ? (((l & 63) << 6) | (l >> 6)) : l;
    unsafeAtomicAdd(&ytot[((size_t)(b*LL) + pos)*DI + d], (p0+p1)+(p2+p3));
    l += dir; pd += pinc; pu += pinc; pbc += bcinc;
  }
}

// ---------------- K5: LayerNorm + silu(z) gate + out_proj (32 rows/block)
__global__ __launch_bounds__(384) void k5_final(const float* __restrict__ ytot,
    const float* __restrict__ zs, const float* __restrict__ g,
    const float* __restrict__ bb, const float* __restrict__ ow,
    float* __restrict__ out)
{
  __shared__ float yt[32][DI+4];      // stride 196 floats, f4-aligned
  __shared__ float muS[32], rsS[32];
  int blk = blockIdx.x;
  int b = blk >> 7; int l0 = (blk & 127) << 5;
  int tid = threadIdx.x;
  // A: stage 32x192 tile
  for (int idx = tid; idx < 32*48; idx += 384) {
    int r = idx / 48, jj = idx % 48;
    ((float4*)yt[r])[jj] = *(const float4*)(ytot + ((size_t)(b*LL) + l0 + r)*DI + 4*jj);
  }
  __syncthreads();
  // B: LayerNorm stats, 8 threads/row
  if (tid < 256) {
    int r = tid >> 3, q = tid & 7;
    const float* row = yt[r];
    float s1 = 0.f, s2 = 0.f;
    #pragma unroll
    for (int i = 0; i < 24; ++i) {
      float v = row[q*24 + i];
      s1 += v; s2 += v*v;
    }
    s1 += __shfl_xor(s1, 1); s2 += __shfl_xor(s2, 1);
    s1 += __shfl_xor(s1, 2); s2 += __shfl_xor(s2, 2);
    s1 += __shfl_xor(s1, 4); s2 += __shfl_xor(s2, 4);
    if (q == 0) {
      float mu = s1 / (float)DI;
      float var = s2 / (float)DI - mu*mu;
      muS[r] = mu;
      rsS[r] = rsqrtf(var + 1e-5f);
    }
  }
  __syncthreads();
  // C: normalize + gate
  for (int idx = tid; idx < 32*48; idx += 384) {
    int r = idx / 48, jj = idx % 48;
    float4 y = ((float4*)yt[r])[jj];
    float mu = muS[r], rs = rsS[r];
    float4 g4 = *(const float4*)(g + 4*jj);
    float4 b4 = *(const float4*)(bb + 4*jj);
    float4 z4 = *(const float4*)(zs + ((size_t)(b*LL) + l0 + r)*DI + 4*jj);
    float4 v;
    v.x = fmaf((y.x-mu)*rs, g4.x, b4.x) * z4.x;
    v.y = fmaf((y.y-mu)*rs, g4.y, b4.y) * z4.y;
    v.z = fmaf((y.z-mu)*rs, g4.z, b4.z) * z4.z;
    v.w = fmaf((y.w-mu)*rs, g4.w, b4.w) * z4.w;
    ((float4*)yt[r])[jj] = v;
  }
  __syncthreads();
  // D: out_proj — thread (c, rg): col c, 8 rows; weights in regs
  {
    int c = tid % 96;
    int rg = tid / 96;            // 0..3
    const float4* wrow = (const float4*)(ow + (size_t)c*DI);
    float4 acc[8];
    #pragma unroll
    for (int rr = 0; rr < 8; ++rr) acc[rr] = make_float4(0.f,0.f,0.f,0.f);
    #pragma unroll
    for (int ch = 0; ch < 6; ++ch) {
      float4 wreg[8];
      #pragma unroll
      for (int jj = 0; jj < 8; ++jj) wreg[jj] = wrow[ch*8 + jj];
      #pragma unroll
      for (int rr = 0; rr < 8; ++rr) {
        const float4* yr = (const float4*)yt[rg*8 + rr];
        #pragma unroll
        for (int jj = 0; jj < 8; ++jj) fma4(acc[rr], wreg[jj], yr[ch*8 + jj]);
      }
    }
    #pragma unroll
    for (int rr = 0; rr < 8; ++rr) {
      float v = (acc[rr].x+acc[rr].y)+(acc[rr].z+acc[rr].w);
      out[((size_t)(b*LL) + l0 + rg*8 + rr)*DM + c] = v;
    }
  }
}

extern "C" void kernel_launch(void* const* d_in, const int* in_sizes, int n_in,
                              void* d_out, int out_size, void* d_ws, size_t ws_size,
                              hipStream_t stream)
{
  const float* x    = (const float*)d_in[0];
  const float* ipw  = (const float*)d_in[1];
  const float* cw   = (const float*)d_in[2];
  const float* cb   = (const float*)d_in[3];
  const float* xpw  = (const float*)d_in[4];
  const float* dtwp = (const float*)d_in[5];
  const float* dtbp = (const float*)d_in[6];
  const float* alog = (const float*)d_in[7];
  const float* dsp  = (const float*)d_in[8];
  const float* ng   = (const float*)d_in[9];
  const float* nbp  = (const float*)d_in[10];
  const float* owp  = (const float*)d_in[11];
  float* out = (float*)d_out;

  float* ws = (float*)d_ws;
  size_t off = 0;
  float* ytot = ws + off; off += (size_t)BN*LL*DI;
  float* zs   = ws + off; off += (size_t)BN*LL*DI;
  float* xi   = ws + off; off += (size_t)BN*LL*DI;
  float* U0   = ws + off; off += (size_t)BN*LL*DI;
  float* U1   = ws + off; off += (size_t)BN*LL*DI;
  float* dlt  = ws + off; off += (size_t)BN*KK*LL*DI;
  float* BCs  = ws + off; off += (size_t)BN*KK*LL*32;
  float* hst  = ws + off; off += (size_t)BN*KK*NCH*DI*NS;
  float* Ssum = ws + off; off += (size_t)BN*KK*NCH*DI;
  (void)ws_size; (void)in_sizes; (void)n_in; (void)out_size;

  hipMemsetAsync(ytot, 0, (size_t)BN*LL*DI*sizeof(float), stream);
  k1_inproj<<<dim3(BN*256), dim3(256), 0, stream>>>(x, ipw, xi, zs);
  k2_conv<<<dim3((BN*LL*48 + 255)/256), dim3(256), 0, stream>>>(xi, cw, cb, U0, U1);
  k3_xproj<<<dim3(BN*KK*256), dim3(256), 0, stream>>>(U0, U1, xpw, dtwp, dtbp, dlt, BCs);
  k4a_pass1<<<dim3(BN*KK*NCH), dim3(192), 0, stream>>>(dlt, U0, U1, BCs, alog, hst, Ssum);
  k4b_combine<<<dim3(BN*KK*12), dim3(256), 0, stream>>>(hst, Ssum, alog);
  k4c_pass2<<<dim3(BN*KK*NCH), dim3(192), 0, stream>>>(dlt, U0, U1, BCs, alog, dsp, hst, ytot);
  k5_final<<<dim3(BN*128), dim3(384), 0, stream>>>(ytot, zs, ng, nbp, owp, out);
}

// Round 7
// 388.606 us; speedup vs baseline: 1.4509x; 1.0435x over previous
//
#include <hip/hip_runtime.h>
#include <math.h>

#define BN 4
#define LL 4096
#define DM 96
#define DI 192
#define NS 16
#define KK 4
#define RR 6
#define NCH 64
#define LC (LL/NCH)
#define BCW 40   // BC row: [0:16)=B, [16:32)=C, [32:38)=dts, pad 2

__device__ __forceinline__ float silu_f(float x){ return x / (1.f + __expf(-x)); }
__device__ __forceinline__ float softplus_f(float x){
  // stable: max(x,0) + log(1+exp(-|x|)); __logf/__expf fine at our tolerance
  return fmaxf(x, 0.f) + __logf(1.f + __expf(-fabsf(x)));
}
__device__ __forceinline__ void fma4(float4& a, const float4 w, const float4 v){
  a.x = fmaf(w.x, v.x, a.x); a.y = fmaf(w.y, v.y, a.y);
  a.z = fmaf(w.z, v.z, a.z); a.w = fmaf(w.w, v.w, a.w);
}

// ---------------- K1: in_proj GEMM: x(B,L,96) @ W^T(384,96) -> xi(B,L,192), zs=silu(z)
__global__ __launch_bounds__(256) void k1_inproj(const float* __restrict__ x,
    const float* __restrict__ w, float* __restrict__ xi, float* __restrict__ zs)
{
  __shared__ float xt[16][DM];
  __shared__ float wt[64][DM+4];
  int blk = blockIdx.x;
  int b = blk >> 8;
  int l0 = (blk & 255) << 4;
  int tid = threadIdx.x;
  for (int idx = tid; idx < 16*24; idx += 256) {
    int t = idx / 24, jj = idx % 24;
    ((float4*)xt[t])[jj] = *(const float4*)(x + ((size_t)(b*LL + l0 + t))*DM + 4*jj);
  }
  int cl = tid & 63;
  int tb = (tid >> 6) * 4;
  for (int ct = 0; ct < 6; ++ct) {
    int c0 = ct*64;
    __syncthreads();
    for (int idx = tid; idx < 64*24; idx += 256) {
      int r = idx / 24, jj = idx % 24;
      ((float4*)wt[r])[jj] = *(const float4*)(w + (size_t)(c0 + r)*DM + 4*jj);
    }
    __syncthreads();
    float4 a0={0,0,0,0}, a1={0,0,0,0}, a2={0,0,0,0}, a3={0,0,0,0};
    const float4* wr = (const float4*)wt[cl];
    const float4* x0 = (const float4*)xt[tb+0];
    const float4* x1 = (const float4*)xt[tb+1];
    const float4* x2 = (const float4*)xt[tb+2];
    const float4* x3 = (const float4*)xt[tb+3];
    #pragma unroll
    for (int jj = 0; jj < 24; ++jj) {
      float4 w4 = wr[jj];
      fma4(a0, w4, x0[jj]); fma4(a1, w4, x1[jj]);
      fma4(a2, w4, x2[jj]); fma4(a3, w4, x3[jj]);
    }
    float accs[4] = { (a0.x+a0.y)+(a0.z+a0.w), (a1.x+a1.y)+(a1.z+a1.w),
                      (a2.x+a2.y)+(a2.z+a2.w), (a3.x+a3.y)+(a3.z+a3.w) };
    int c = c0 + cl;
    #pragma unroll
    for (int tt = 0; tt < 4; ++tt) {
      int l = l0 + tb + tt;
      float v = accs[tt];
      if (c < DI) xi[((size_t)(b*LL + l))*DI + c] = v;
      else        zs[((size_t)(b*LL + l))*DI + (c - DI)] = silu_f(v);
    }
  }
}

// ---------------- K2: depthwise 3x3 conv SAME + bias + SiLU, 4 channels/thread.
__global__ __launch_bounds__(256) void k2_conv(const float* __restrict__ xi,
    const float* __restrict__ cw, const float* __restrict__ cb,
    float* __restrict__ U0, float* __restrict__ U1)
{
  int n = blockIdx.x*256 + threadIdx.x;
  if (n >= BN*LL*48) return;
  int c4 = n % 48;
  int w_ = (n / 48) & 63;
  int h_ = (n / (48*64)) & 63;
  int b  = n / (48*LL);
  int c  = c4 * 4;
  float4 acc = { cb[c], cb[c+1], cb[c+2], cb[c+3] };
  #pragma unroll
  for (int kh = 0; kh < 3; ++kh) {
    int hh = h_ + kh - 1;
    if (hh < 0 || hh >= 64) continue;
    #pragma unroll
    for (int kw = 0; kw < 3; ++kw) {
      int ww2 = w_ + kw - 1;
      if (ww2 < 0 || ww2 >= 64) continue;
      float4 v = *(const float4*)(xi + ((size_t)(b*LL) + hh*64 + ww2)*DI + c);
      int tap = kh*3 + kw;
      acc.x = fmaf(v.x, cw[(c+0)*9 + tap], acc.x);
      acc.y = fmaf(v.y, cw[(c+1)*9 + tap], acc.y);
      acc.z = fmaf(v.z, cw[(c+2)*9 + tap], acc.z);
      acc.w = fmaf(v.w, cw[(c+3)*9 + tap], acc.w);
    }
  }
  float4 o = { silu_f(acc.x), silu_f(acc.y), silu_f(acc.z), silu_f(acc.w) };
  *(float4*)(U0 + ((size_t)(b*LL) + h_*64 + w_)*DI + c) = o;
  *(float4*)(U1 + ((size_t)(b*LL) + w_*64 + h_)*DI + c) = o;
}

// ---------------- K3: x_proj GEMM only (38 cols), store permuted 40-wide rows.
// 32 rows/block, 320 threads = 8 rowgroups x 40 cols (38 active).
// Each thread: 4 rows x 1 col, 16 independent FMA chains.
__global__ __launch_bounds__(320) void k3_xproj(const float* __restrict__ U0,
    const float* __restrict__ U1, const float* __restrict__ xw,
    float* __restrict__ BC)
{
  __shared__ float  ut[32][DI];      // 24.6 KB, broadcast reads
  __shared__ float4 wT[48][41];      // 31.5 KB, wT[jj][cc], +pad col
  __shared__ float  cS[32][BCW];     // 5.1 KB
  int blk = blockIdx.x;
  int tile = blk & 127; int k = (blk >> 7) & 3; int b = blk >> 9;
  int l0 = tile << 5;
  int tid = threadIdx.x;
  const float* U = (k & 1) ? U1 : U0;
  int b4k = b*KK + k;
  for (int idx = tid; idx < 32*48; idx += 320) {
    int r = idx / 48, jj = idx % 48;
    ((float4*)ut[r])[jj] = *(const float4*)(U + ((size_t)(b*LL + l0 + r))*DI + 4*jj);
  }
  for (int idx = tid; idx < 38*48; idx += 320) {
    int cc = idx / 48, jj = idx % 48;
    wT[jj][cc] = *(const float4*)(xw + (size_t)(k*38 + cc)*DI + 4*jj);
  }
  __syncthreads();
  int cc = tid % 40;
  int rg = tid / 40;                 // 0..7
  if (cc < 38) {
    float4 a0={0,0,0,0}, a1={0,0,0,0}, a2={0,0,0,0}, a3={0,0,0,0};
    const float4* u0 = (const float4*)ut[rg*4+0];
    const float4* u1 = (const float4*)ut[rg*4+1];
    const float4* u2 = (const float4*)ut[rg*4+2];
    const float4* u3 = (const float4*)ut[rg*4+3];
    #pragma unroll
    for (int jj = 0; jj < 48; ++jj) {
      float4 w4 = wT[jj][cc];
      fma4(a0, w4, u0[jj]); fma4(a1, w4, u1[jj]);
      fma4(a2, w4, u2[jj]); fma4(a3, w4, u3[jj]);
    }
    int cp = (cc < RR) ? (32 + cc) : (cc - RR);   // B->0..15, C->16..31, dts->32..37
    cS[rg*4+0][cp] = (a0.x+a0.y)+(a0.z+a0.w);
    cS[rg*4+1][cp] = (a1.x+a1.y)+(a1.z+a1.w);
    cS[rg*4+2][cp] = (a2.x+a2.y)+(a2.z+a2.w);
    cS[rg*4+3][cp] = (a3.x+a3.y)+(a3.z+a3.w);
  } else {
    cS[rg*4+0][cc] = 0.f; cS[rg*4+1][cc] = 0.f;
    cS[rg*4+2][cc] = 0.f; cS[rg*4+3][cc] = 0.f;
  }
  __syncthreads();
  {
    int r = tid / 10, q = tid % 10;  // 320 items exactly
    *(float4*)(BC + ((size_t)b4k*LL + l0 + r)*BCW + 4*q) = ((float4*)cS[r])[q];
  }
}

// ---- exp-power tree: ep[n] = e1^(n+1), log depth
__device__ __forceinline__ void pow_tree(float e1, float* ep){
  ep[0]=e1;
  ep[1]=e1*e1;
  ep[2]=ep[1]*e1;  ep[3]=ep[1]*ep[1];
  ep[4]=ep[3]*e1;  ep[5]=ep[3]*ep[1]; ep[6]=ep[3]*ep[2]; ep[7]=ep[3]*ep[3];
  #pragma unroll
  for (int i=0;i<8;++i) ep[8+i]=ep[7]*ep[i];
}

// delta from BC row + per-lane dt weights
__device__ __forceinline__ float delta_of(const float* __restrict__ row,
    const float* __restrict__ dw, float dtb1){
  float4 t4 = *(const float4*)(row + 32);
  float2 t2 = *(const float2*)(row + 36);
  float a = dtb1;
  a = fmaf(t4.x, dw[0], a); a = fmaf(t4.y, dw[1], a);
  a = fmaf(t4.z, dw[2], a); a = fmaf(t4.w, dw[3], a);
  a = fmaf(t2.x, dw[4], a); a = fmaf(t2.y, dw[5], a);
  return softplus_f(a);
}

// ---------------- K4a: scan pass 1 — per-chunk local scan -> hend, sum(delta)
__global__ __launch_bounds__(192) void k4a_pass1(const float* __restrict__ U0,
    const float* __restrict__ U1, const float* __restrict__ BC,
    const float* __restrict__ A_logs, const float* __restrict__ dtw,
    const float* __restrict__ dtb,
    float* __restrict__ hst, float* __restrict__ Ssum)
{
  int blk = blockIdx.x;
  int c = blk % NCH; int k = (blk / NCH) & 3; int b = blk / (NCH*4);
  int d = threadIdx.x;
  const float* U = (k & 1) ? U1 : U0;
  int b4k = b*KK + k;
  float an[NS];
  #pragma unroll
  for (int n = 0; n < NS; ++n) an[n] = -__expf(A_logs[(k*DI + d)*NS + n]);
  float a0 = an[0];
  bool chain = true;
  #pragma unroll
  for (int n = 1; n < NS; ++n)
    chain = chain && (fabsf(an[n] - a0*(float)(n+1)) <= 1e-3f*(float)(n+1));
  float dw[RR];
  #pragma unroll
  for (int r = 0; r < RR; ++r) dw[r] = dtw[(k*DI + d)*RR + r];
  float dtb1 = dtb[k*DI + d];
  float h[NS];
  #pragma unroll
  for (int n = 0; n < NS; ++n) h[n] = 0.f;
  float sd = 0.f;
  bool fwd = (k < 2);
  int lo = c * LC;
  int dir = fwd ? 1 : -1;
  int l = fwd ? lo : (lo + LC - 1);
  const float* pu = U + ((size_t)(b*LL) + l)*DI + d;
  const float* pbc = BC + ((size_t)b4k*LL + l)*BCW;
  intptr_t pinc = (intptr_t)dir * DI;
  intptr_t bcinc = (intptr_t)dir * BCW;
  #pragma unroll 2
  for (int s = 0; s < LC; ++s) {
    float dv = delta_of(pbc, dw, dtb1);
    float u  = *pu;
    float du = dv * u;
    sd += dv;
    const float4* b4p = (const float4*)pbc;
    float4 B0 = b4p[0], B1 = b4p[1], B2 = b4p[2], B3 = b4p[3];
    float Bv[NS] = {B0.x,B0.y,B0.z,B0.w, B1.x,B1.y,B1.z,B1.w,
                    B2.x,B2.y,B2.z,B2.w, B3.x,B3.y,B3.z,B3.w};
    if (chain) {
      float ep[NS];
      pow_tree(__expf(a0 * dv), ep);
      #pragma unroll
      for (int n = 0; n < NS; ++n) h[n] = fmaf(ep[n], h[n], du*Bv[n]);
    } else {
      #pragma unroll
      for (int n = 0; n < NS; ++n) h[n] = fmaf(__expf(an[n]*dv), h[n], du*Bv[n]);
    }
    pu += pinc; pbc += bcinc;
  }
  size_t base = ((size_t)b4k*NCH + c)*DI + d;
  float4* he = (float4*)(hst + base*NS);
  he[0] = make_float4(h[0], h[1], h[2], h[3]);
  he[1] = make_float4(h[4], h[5], h[6], h[7]);
  he[2] = make_float4(h[8], h[9], h[10],h[11]);
  he[3] = make_float4(h[12],h[13],h[14],h[15]);
  Ssum[base] = sd;
}

// ---------------- K4b: combine — prefix chunk states in place (hend -> hin)
__global__ __launch_bounds__(256) void k4b_combine(float* __restrict__ hst,
    const float* __restrict__ Ssum, const float* __restrict__ A_logs)
{
  int blk = blockIdx.x;
  int dgrp = blk % 12; int k = (blk/12) & 3; int b = blk/48;
  int tid = threadIdx.x;
  int d = dgrp*16 + (tid >> 4);
  int n = tid & 15;
  int b4k = b*KK + k;
  float an = -__expf(A_logs[(k*DI + d)*NS + n]);
  bool fwd = (k < 2);
  float h = 0.f;
  for (int s = 0; s < NCH; ++s) {
    int c = fwd ? s : (NCH - 1 - s);
    size_t base = ((size_t)b4k*NCH + c)*DI + d;
    float he = hst[base*NS + n];
    hst[base*NS + n] = h;
    h = __expf(an * Ssum[base]) * h + he;
  }
}

// ---------------- K4c: scan pass 2 — full scan from hin, emit y (atomic merge)
__global__ __launch_bounds__(192) void k4c_pass2(const float* __restrict__ U0,
    const float* __restrict__ U1, const float* __restrict__ BC,
    const float* __restrict__ A_logs, const float* __restrict__ dtw,
    const float* __restrict__ dtb, const float* __restrict__ Dsv,
    const float* __restrict__ hst, float* __restrict__ ytot)
{
  int blk = blockIdx.x;
  int c = blk % NCH; int k = (blk / NCH) & 3; int b = blk / (NCH*4);
  int d = threadIdx.x;
  const float* U = (k & 1) ? U1 : U0;
  int b4k = b*KK + k;
  float an[NS];
  #pragma unroll
  for (int n = 0; n < NS; ++n) an[n] = -__expf(A_logs[(k*DI + d)*NS + n]);
  float a0 = an[0];
  bool chain = true;
  #pragma unroll
  for (int n = 1; n < NS; ++n)
    chain = chain && (fabsf(an[n] - a0*(float)(n+1)) <= 1e-3f*(float)(n+1));
  float dw[RR];
  #pragma unroll
  for (int r = 0; r < RR; ++r) dw[r] = dtw[(k*DI + d)*RR + r];
  float dtb1 = dtb[k*DI + d];
  float Dd = Dsv[k*DI + d];
  size_t base = ((size_t)b4k*NCH + c)*DI + d;
  float h[NS];
  {
    const float4* hi = (const float4*)(hst + base*NS);
    float4 h0 = hi[0], h1 = hi[1], h2 = hi[2], h3 = hi[3];
    h[0]=h0.x; h[1]=h0.y; h[2]=h0.z; h[3]=h0.w;
    h[4]=h1.x; h[5]=h1.y; h[6]=h1.z; h[7]=h1.w;
    h[8]=h2.x; h[9]=h2.y; h[10]=h2.z; h[11]=h2.w;
    h[12]=h3.x; h[13]=h3.y; h[14]=h3.z; h[15]=h3.w;
  }
  bool fwd = (k < 2);
  int lo = c * LC;
  int dir = fwd ? 1 : -1;
  int l = fwd ? lo : (lo + LC - 1);
  const float* pu = U + ((size_t)(b*LL) + l)*DI + d;
  const float* pbc = BC + ((size_t)b4k*LL + l)*BCW;
  intptr_t pinc = (intptr_t)dir * DI;
  intptr_t bcinc = (intptr_t)dir * BCW;
  bool odd = (k & 1);
  #pragma unroll 2
  for (int s = 0; s < LC; ++s) {
    float dv = delta_of(pbc, dw, dtb1);
    float u  = *pu;
    float du = dv * u;
    const float4* b4p = (const float4*)pbc;
    float4 B0 = b4p[0], B1 = b4p[1], B2 = b4p[2], B3 = b4p[3];
    float4 C0 = b4p[4], C1 = b4p[5], C2 = b4p[6], C3 = b4p[7];
    float Bv[NS] = {B0.x,B0.y,B0.z,B0.w, B1.x,B1.y,B1.z,B1.w,
                    B2.x,B2.y,B2.z,B2.w, B3.x,B3.y,B3.z,B3.w};
    float Cv[NS] = {C0.x,C0.y,C0.z,C0.w, C1.x,C1.y,C1.z,C1.w,
                    C2.x,C2.y,C2.z,C2.w, C3.x,C3.y,C3.z,C3.w};
    if (chain) {
      float ep[NS];
      pow_tree(__expf(a0 * dv), ep);
      #pragma unroll
      for (int n = 0; n < NS; ++n) h[n] = fmaf(ep[n], h[n], du*Bv[n]);
    } else {
      #pragma unroll
      for (int n = 0; n < NS; ++n) h[n] = fmaf(__expf(an[n]*dv), h[n], du*Bv[n]);
    }
    float p0 = Dd*u, p1 = 0.f, p2 = 0.f, p3 = 0.f;
    #pragma unroll
    for (int n = 0; n < NS; n += 4) {
      p0 = fmaf(h[n+0], Cv[n+0], p0);
      p1 = fmaf(h[n+1], Cv[n+1], p1);
      p2 = fmaf(h[n+2], Cv[n+2], p2);
      p3 = fmaf(h[n+3], Cv[n+3], p3);
    }
    int pos = odd ? (((l & 63) << 6) | (l >> 6)) : l;
    unsafeAtomicAdd(&ytot[((size_t)(b*LL) + pos)*DI + d], (p0+p1)+(p2+p3));
    l += dir; pu += pinc; pbc += bcinc;
  }
}

// ---------------- K5: LayerNorm + silu(z) gate + out_proj (32 rows/block)
__global__ __launch_bounds__(384) void k5_final(const float* __restrict__ ytot,
    const float* __restrict__ zs, const float* __restrict__ g,
    const float* __restrict__ bb, const float* __restrict__ ow,
    float* __restrict__ out)
{
  __shared__ float yt[32][DI+4];
  __shared__ float muS[32], rsS[32];
  int blk = blockIdx.x;
  int b = blk >> 7; int l0 = (blk & 127) << 5;
  int tid = threadIdx.x;
  for (int idx = tid; idx < 32*48; idx += 384) {
    int r = idx / 48, jj = idx % 48;
    ((float4*)yt[r])[jj] = *(const float4*)(ytot + ((size_t)(b*LL) + l0 + r)*DI + 4*jj);
  }
  __syncthreads();
  if (tid < 256) {
    int r = tid >> 3, q = tid & 7;
    const float* row = yt[r];
    float s1 = 0.f, s2 = 0.f;
    #pragma unroll
    for (int i = 0; i < 24; ++i) {
      float v = row[q*24 + i];
      s1 += v; s2 += v*v;
    }
    s1 += __shfl_xor(s1, 1); s2 += __shfl_xor(s2, 1);
    s1 += __shfl_xor(s1, 2); s2 += __shfl_xor(s2, 2);
    s1 += __shfl_xor(s1, 4); s2 += __shfl_xor(s2, 4);
    if (q == 0) {
      float mu = s1 / (float)DI;
      float var = s2 / (float)DI - mu*mu;
      muS[r] = mu;
      rsS[r] = rsqrtf(var + 1e-5f);
    }
  }
  __syncthreads();
  for (int idx = tid; idx < 32*48; idx += 384) {
    int r = idx / 48, jj = idx % 48;
    float4 y = ((float4*)yt[r])[jj];
    float mu = muS[r], rs = rsS[r];
    float4 g4 = *(const float4*)(g + 4*jj);
    float4 b4 = *(const float4*)(bb + 4*jj);
    float4 z4 = *(const float4*)(zs + ((size_t)(b*LL) + l0 + r)*DI + 4*jj);
    float4 v;
    v.x = fmaf((y.x-mu)*rs, g4.x, b4.x) * z4.x;
    v.y = fmaf((y.y-mu)*rs, g4.y, b4.y) * z4.y;
    v.z = fmaf((y.z-mu)*rs, g4.z, b4.z) * z4.z;
    v.w = fmaf((y.w-mu)*rs, g4.w, b4.w) * z4.w;
    ((float4*)yt[r])[jj] = v;
  }
  __syncthreads();
  {
    int c = tid % 96;
    int rg = tid / 96;
    const float4* wrow = (const float4*)(ow + (size_t)c*DI);
    float4 acc[8];
    #pragma unroll
    for (int rr = 0; rr < 8; ++rr) acc[rr] = make_float4(0.f,0.f,0.f,0.f);
    #pragma unroll
    for (int ch = 0; ch < 6; ++ch) {
      float4 wreg[8];
      #pragma unroll
      for (int jj = 0; jj < 8; ++jj) wreg[jj] = wrow[ch*8 + jj];
      #pragma unroll
      for (int rr = 0; rr < 8; ++rr) {
        const float4* yr = (const float4*)yt[rg*8 + rr];
        #pragma unroll
        for (int jj = 0; jj < 8; ++jj) fma4(acc[rr], wreg[jj], yr[ch*8 + jj]);
      }
    }
    #pragma unroll
    for (int rr = 0; rr < 8; ++rr) {
      float v = (acc[rr].x+acc[rr].y)+(acc[rr].z+acc[rr].w);
      out[((size_t)(b*LL) + l0 + rg*8 + rr)*DM + c] = v;
    }
  }
}

extern "C" void kernel_launch(void* const* d_in, const int* in_sizes, int n_in,
                              void* d_out, int out_size, void* d_ws, size_t ws_size,
                              hipStream_t stream)
{
  const float* x    = (const float*)d_in[0];
  const float* ipw  = (const float*)d_in[1];
  const float* cw   = (const float*)d_in[2];
  const float* cb   = (const float*)d_in[3];
  const float* xpw  = (const float*)d_in[4];
  const float* dtwp = (const float*)d_in[5];
  const float* dtbp = (const float*)d_in[6];
  const float* alog = (const float*)d_in[7];
  const float* dsp  = (const float*)d_in[8];
  const float* ng   = (const float*)d_in[9];
  const float* nbp  = (const float*)d_in[10];
  const float* owp  = (const float*)d_in[11];
  float* out = (float*)d_out;

  float* ws = (float*)d_ws;
  size_t off = 0;
  float* ytot = ws + off; off += (size_t)BN*LL*DI;
  float* zs   = ws + off; off += (size_t)BN*LL*DI;
  float* xi   = ws + off; off += (size_t)BN*LL*DI;
  float* U0   = ws + off; off += (size_t)BN*LL*DI;
  float* U1   = ws + off; off += (size_t)BN*LL*DI;
  float* BC   = ws + off; off += (size_t)BN*KK*LL*BCW;
  float* hst  = ws + off; off += (size_t)BN*KK*NCH*DI*NS;
  float* Ssum = ws + off; off += (size_t)BN*KK*NCH*DI;
  (void)ws_size; (void)in_sizes; (void)n_in; (void)out_size;

  hipMemsetAsync(ytot, 0, (size_t)BN*LL*DI*sizeof(float), stream);
  k1_inproj<<<dim3(BN*256), dim3(256), 0, stream>>>(x, ipw, xi, zs);
  k2_conv<<<dim3((BN*LL*48 + 255)/256), dim3(256), 0, stream>>>(xi, cw, cb, U0, U1);
  k3_xproj<<<dim3(BN*KK*128), dim3(320), 0, stream>>>(U0, U1, xpw, BC);
  k4a_pass1<<<dim3(BN*KK*NCH), dim3(192), 0, stream>>>(U0, U1, BC, alog, dtwp, dtbp, hst, Ssum);
  k4b_combine<<<dim3(BN*KK*12), dim3(256), 0, stream>>>(hst, Ssum, alog);
  k4c_pass2<<<dim3(BN*KK*NCH), dim3(192), 0, stream>>>(U0, U1, BC, alog, dtwp, dtbp, dsp, hst, ytot);
  k5_final<<<dim3(BN*128), dim3(384), 0, stream>>>(ytot, zs, ng, nbp, owp, out);
}

// Round 11
// 337.457 us; speedup vs baseline: 1.6708x; 1.1516x over previous
//
#include <hip/hip_runtime.h>
#include <math.h>

#define BN 4
#define LL 4096
#define DM 96
#define DI 192
#define NS 16
#define KK 4
#define RR 6
#define NCH 64
#define LC (LL/NCH)
#define BCW 40   // BC row: [0:16)=B, [16:32)=C, [32:38)=dts, pad 2

__device__ __forceinline__ float silu_f(float x){ return x / (1.f + __expf(-x)); }
__device__ __forceinline__ float softplus_f(float x){
  return fmaxf(x, 0.f) + __logf(1.f + __expf(-fabsf(x)));
}
__device__ __forceinline__ void fma4(float4& a, const float4 w, const float4 v){
  a.x = fmaf(w.x, v.x, a.x); a.y = fmaf(w.y, v.y, a.y);
  a.z = fmaf(w.z, v.z, a.z); a.w = fmaf(w.w, v.w, a.w);
}

// ---------------- K1: in_proj GEMM: x(B,L,96) @ W^T(384,96) -> xi(B,L,192), zs=silu(z)
// k5-D pattern: 16 rows/block, 384 threads = 1 col/thread, W row streamed from
// global (L2-resident), x tile 6KB LDS broadcast, 16 independent f4 partial sums.
__global__ __launch_bounds__(384) void k1_inproj(const float* __restrict__ x,
    const float* __restrict__ w, float* __restrict__ xi, float* __restrict__ zs)
{
  __shared__ float xt[16][DM];       // 6 KB
  int blk = blockIdx.x;
  int b = blk >> 8;
  int l0 = (blk & 255) << 4;
  int tid = threadIdx.x;             // col c in [0,384)
  {
    int t = tid / 24, jj = tid % 24; // 384 = 16*24, one f4 per thread
    ((float4*)xt[t])[jj] = *(const float4*)(x + ((size_t)(b*LL + l0 + t))*DM + 4*jj);
  }
  __syncthreads();
  const float4* wrow = (const float4*)(w + (size_t)tid*DM);
  float4 acc[16];
  #pragma unroll
  for (int r = 0; r < 16; ++r) acc[r] = make_float4(0.f,0.f,0.f,0.f);
  #pragma unroll 4
  for (int jj = 0; jj < 24; ++jj) {
    float4 w4 = wrow[jj];
    #pragma unroll
    for (int r = 0; r < 16; ++r) fma4(acc[r], w4, ((const float4*)xt[r])[jj]);
  }
  if (tid < DI) {
    #pragma unroll
    for (int r = 0; r < 16; ++r) {
      float v = (acc[r].x+acc[r].y)+(acc[r].z+acc[r].w);
      xi[((size_t)(b*LL + l0 + r))*DI + tid] = v;
    }
  } else {
    #pragma unroll
    for (int r = 0; r < 16; ++r) {
      float v = (acc[r].x+acc[r].y)+(acc[r].z+acc[r].w);
      zs[((size_t)(b*LL + l0 + r))*DI + (tid - DI)] = silu_f(v);
    }
  }
}

// ---------------- K2: depthwise 3x3 conv SAME + bias + SiLU, 4 channels/thread.
__global__ __launch_bounds__(256) void k2_conv(const float* __restrict__ xi,
    const float* __restrict__ cw, const float* __restrict__ cb,
    float* __restrict__ U0, float* __restrict__ U1)
{
  int n = blockIdx.x*256 + threadIdx.x;
  if (n >= BN*LL*48) return;
  int c4 = n % 48;
  int w_ = (n / 48) & 63;
  int h_ = (n / (48*64)) & 63;
  int b  = n / (48*LL);
  int c  = c4 * 4;
  float4 acc = { cb[c], cb[c+1], cb[c+2], cb[c+3] };
  #pragma unroll
  for (int kh = 0; kh < 3; ++kh) {
    int hh = h_ + kh - 1;
    if (hh < 0 || hh >= 64) continue;
    #pragma unroll
    for (int kw = 0; kw < 3; ++kw) {
      int ww2 = w_ + kw - 1;
      if (ww2 < 0 || ww2 >= 64) continue;
      float4 v = *(const float4*)(xi + ((size_t)(b*LL) + hh*64 + ww2)*DI + c);
      int tap = kh*3 + kw;
      acc.x = fmaf(v.x, cw[(c+0)*9 + tap], acc.x);
      acc.y = fmaf(v.y, cw[(c+1)*9 + tap], acc.y);
      acc.z = fmaf(v.z, cw[(c+2)*9 + tap], acc.z);
      acc.w = fmaf(v.w, cw[(c+3)*9 + tap], acc.w);
    }
  }
  float4 o = { silu_f(acc.x), silu_f(acc.y), silu_f(acc.z), silu_f(acc.w) };
  *(float4*)(U0 + ((size_t)(b*LL) + h_*64 + w_)*DI + c) = o;
  *(float4*)(U1 + ((size_t)(b*LL) + w_*64 + h_)*DI + c) = o;
}

// ---------------- K3: x_proj GEMM only (38 cols), store permuted 40-wide rows.
__global__ __launch_bounds__(320) void k3_xproj(const float* __restrict__ U0,
    const float* __restrict__ U1, const float* __restrict__ xw,
    float* __restrict__ BC)
{
  __shared__ float  ut[32][DI];      // 24.6 KB, broadcast reads
  __shared__ float4 wT[48][41];      // 31.5 KB, wT[jj][cc], +pad col
  __shared__ float  cS[32][BCW];     // 5.1 KB
  int blk = blockIdx.x;
  int tile = blk & 127; int k = (blk >> 7) & 3; int b = blk >> 9;
  int l0 = tile << 5;
  int tid = threadIdx.x;
  const float* U = (k & 1) ? U1 : U0;
  int b4k = b*KK + k;
  for (int idx = tid; idx < 32*48; idx += 320) {
    int r = idx / 48, jj = idx % 48;
    ((float4*)ut[r])[jj] = *(const float4*)(U + ((size_t)(b*LL + l0 + r))*DI + 4*jj);
  }
  for (int idx = tid; idx < 38*48; idx += 320) {
    int cc = idx / 48, jj = idx % 48;
    wT[jj][cc] = *(const float4*)(xw + (size_t)(k*38 + cc)*DI + 4*jj);
  }
  __syncthreads();
  int cc = tid % 40;
  int rg = tid / 40;                 // 0..7
  if (cc < 38) {
    float4 a0={0,0,0,0}, a1={0,0,0,0}, a2={0,0,0,0}, a3={0,0,0,0};
    const float4* u0 = (const float4*)ut[rg*4+0];
    const float4* u1 = (const float4*)ut[rg*4+1];
    const float4* u2 = (const float4*)ut[rg*4+2];
    const float4* u3 = (const float4*)ut[rg*4+3];
    #pragma unroll
    for (int jj = 0; jj < 48; ++jj) {
      float4 w4 = wT[jj][cc];
      fma4(a0, w4, u0[jj]); fma4(a1, w4, u1[jj]);
      fma4(a2, w4, u2[jj]); fma4(a3, w4, u3[jj]);
    }
    int cp = (cc < RR) ? (32 + cc) : (cc - RR);   // B->0..15, C->16..31, dts->32..37
    cS[rg*4+0][cp] = (a0.x+a0.y)+(a0.z+a0.w);
    cS[rg*4+1][cp] = (a1.x+a1.y)+(a1.z+a1.w);
    cS[rg*4+2][cp] = (a2.x+a2.y)+(a2.z+a2.w);
    cS[rg*4+3][cp] = (a3.x+a3.y)+(a3.z+a3.w);
  } else {
    cS[rg*4+0][cc] = 0.f; cS[rg*4+1][cc] = 0.f;
    cS[rg*4+2][cc] = 0.f; cS[rg*4+3][cc] = 0.f;
  }
  __syncthreads();
  {
    int r = tid / 10, q = tid % 10;  // 320 items exactly
    *(float4*)(BC + ((size_t)b4k*LL + l0 + r)*BCW + 4*q) = ((float4*)cS[r])[q];
  }
}

// ---- exp-power tree: ep[n] = e1^(n+1), log depth
__device__ __forceinline__ void pow_tree(float e1, float* ep){
  ep[0]=e1;
  ep[1]=e1*e1;
  ep[2]=ep[1]*e1;  ep[3]=ep[1]*ep[1];
  ep[4]=ep[3]*e1;  ep[5]=ep[3]*ep[1]; ep[6]=ep[3]*ep[2]; ep[7]=ep[3]*ep[3];
  #pragma unroll
  for (int i=0;i<8;++i) ep[8+i]=ep[7]*ep[i];
}

// delta from BC row + per-lane dt weights
__device__ __forceinline__ float delta_of(const float* __restrict__ row,
    const float* __restrict__ dw, float dtb1){
  float4 t4 = *(const float4*)(row + 32);
  float2 t2 = *(const float2*)(row + 36);
  float a = dtb1;
  a = fmaf(t4.x, dw[0], a); a = fmaf(t4.y, dw[1], a);
  a = fmaf(t4.z, dw[2], a); a = fmaf(t4.w, dw[3], a);
  a = fmaf(t2.x, dw[4], a); a = fmaf(t2.y, dw[5], a);
  return softplus_f(a);
}

// ---------------- K4a: scan pass 1 — per-chunk local scan -> hend, sum(delta)
__global__ __launch_bounds__(192) void k4a_pass1(const float* __restrict__ U0,
    const float* __restrict__ U1, const float* __restrict__ BC,
    const float* __restrict__ A_logs, const float* __restrict__ dtw,
    const float* __restrict__ dtb,
    float* __restrict__ hst, float* __restrict__ Ssum)
{
  int blk = blockIdx.x;
  int c = blk % NCH; int k = (blk / NCH) & 3; int b = blk / (NCH*4);
  int d = threadIdx.x;
  const float* U = (k & 1) ? U1 : U0;
  int b4k = b*KK + k;
  float an[NS];
  #pragma unroll
  for (int n = 0; n < NS; ++n) an[n] = -__expf(A_logs[(k*DI + d)*NS + n]);
  float a0 = an[0];
  bool chain = true;
  #pragma unroll
  for (int n = 1; n < NS; ++n)
    chain = chain && (fabsf(an[n] - a0*(float)(n+1)) <= 1e-3f*(float)(n+1));
  float dw[RR];
  #pragma unroll
  for (int r = 0; r < RR; ++r) dw[r] = dtw[(k*DI + d)*RR + r];
  float dtb1 = dtb[k*DI + d];
  float h[NS];
  #pragma unroll
  for (int n = 0; n < NS; ++n) h[n] = 0.f;
  float sd = 0.f;
  bool fwd = (k < 2);
  int lo = c * LC;
  int dir = fwd ? 1 : -1;
  int l = fwd ? lo : (lo + LC - 1);
  const float* pu = U + ((size_t)(b*LL) + l)*DI + d;
  const float* pbc = BC + ((size_t)b4k*LL + l)*BCW;
  intptr_t pinc = (intptr_t)dir * DI;
  intptr_t bcinc = (intptr_t)dir * BCW;
  #pragma unroll 2
  for (int s = 0; s < LC; ++s) {
    float dv = delta_of(pbc, dw, dtb1);
    float u  = *pu;
    float du = dv * u;
    sd += dv;
    const float4* b4p = (const float4*)pbc;
    float4 B0 = b4p[0], B1 = b4p[1], B2 = b4p[2], B3 = b4p[3];
    float Bv[NS] = {B0.x,B0.y,B0.z,B0.w, B1.x,B1.y,B1.z,B1.w,
                    B2.x,B2.y,B2.z,B2.w, B3.x,B3.y,B3.z,B3.w};
    if (chain) {
      float ep[NS];
      pow_tree(__expf(a0 * dv), ep);
      #pragma unroll
      for (int n = 0; n < NS; ++n) h[n] = fmaf(ep[n], h[n], du*Bv[n]);
    } else {
      #pragma unroll
      for (int n = 0; n < NS; ++n) h[n] = fmaf(__expf(an[n]*dv), h[n], du*Bv[n]);
    }
    pu += pinc; pbc += bcinc;
  }
  size_t base = ((size_t)b4k*NCH + c)*DI + d;
  float4* he = (float4*)(hst + base*NS);
  he[0] = make_float4(h[0], h[1], h[2], h[3]);
  he[1] = make_float4(h[4], h[5], h[6], h[7]);
  he[2] = make_float4(h[8], h[9], h[10],h[11]);
  he[3] = make_float4(h[12],h[13],h[14],h[15]);
  Ssum[base] = sd;
}

// ---------------- K4b: combine — prefix chunk states in place (hend -> hin)
__global__ __launch_bounds__(256) void k4b_combine(float* __restrict__ hst,
    const float* __restrict__ Ssum, const float* __restrict__ A_logs)
{
  int blk = blockIdx.x;
  int dgrp = blk % 12; int k = (blk/12) & 3; int b = blk/48;
  int tid = threadIdx.x;
  int d = dgrp*16 + (tid >> 4);
  int n = tid & 15;
  int b4k = b*KK + k;
  float an = -__expf(A_logs[(k*DI + d)*NS + n]);
  bool fwd = (k < 2);
  float h = 0.f;
  for (int s = 0; s < NCH; ++s) {
    int c = fwd ? s : (NCH - 1 - s);
    size_t base = ((size_t)b4k*NCH + c)*DI + d;
    float he = hst[base*NS + n];
    hst[base*NS + n] = h;
    h = __expf(an * Ssum[base]) * h + he;
  }
}

// ---------------- K4c: scan pass 2 — full scan from hin, emit y (atomic merge)
__global__ __launch_bounds__(192) void k4c_pass2(const float* __restrict__ U0,
    const float* __restrict__ U1, const float* __restrict__ BC,
    const float* __restrict__ A_logs, const float* __restrict__ dtw,
    const float* __restrict__ dtb, const float* __restrict__ Dsv,
    const float* __restrict__ hst, float* __restrict__ ytot)
{
  int blk = blockIdx.x;
  int c = blk % NCH; int k = (blk / NCH) & 3; int b = blk / (NCH*4);
  int d = threadIdx.x;
  const float* U = (k & 1) ? U1 : U0;
  int b4k = b*KK + k;
  float an[NS];
  #pragma unroll
  for (int n = 0; n < NS; ++n) an[n] = -__expf(A_logs[(k*DI + d)*NS + n]);
  float a0 = an[0];
  bool chain = true;
  #pragma unroll
  for (int n = 1; n < NS; ++n)
    chain = chain && (fabsf(an[n] - a0*(float)(n+1)) <= 1e-3f*(float)(n+1));
  float dw[RR];
  #pragma unroll
  for (int r = 0; r < RR; ++r) dw[r] = dtw[(k*DI + d)*RR + r];
  float dtb1 = dtb[k*DI + d];
  float Dd = Dsv[k*DI + d];
  size_t base = ((size_t)b4k*NCH + c)*DI + d;
  float h[NS];
  {
    const float4* hi = (const float4*)(hst + base*NS);
    float4 h0 = hi[0], h1 = hi[1], h2 = hi[2], h3 = hi[3];
    h[0]=h0.x; h[1]=h0.y; h[2]=h0.z; h[3]=h0.w;
    h[4]=h1.x; h[5]=h1.y; h[6]=h1.z; h[7]=h1.w;
    h[8]=h2.x; h[9]=h2.y; h[10]=h2.z; h[11]=h2.w;
    h[12]=h3.x; h[13]=h3.y; h[14]=h3.z; h[15]=h3.w;
  }
  bool fwd = (k < 2);
  int lo = c * LC;
  int dir = fwd ? 1 : -1;
  int l = fwd ? lo : (lo + LC - 1);
  const float* pu = U + ((size_t)(b*LL) + l)*DI + d;
  const float* pbc = BC + ((size_t)b4k*LL + l)*BCW;
  intptr_t pinc = (intptr_t)dir * DI;
  intptr_t bcinc = (intptr_t)dir * BCW;
  bool odd = (k & 1);
  #pragma unroll 2
  for (int s = 0; s < LC; ++s) {
    float dv = delta_of(pbc, dw, dtb1);
    float u  = *pu;
    float du = dv * u;
    const float4* b4p = (const float4*)pbc;
    float4 B0 = b4p[0], B1 = b4p[1], B2 = b4p[2], B3 = b4p[3];
    float4 C0 = b4p[4], C1 = b4p[5], C2 = b4p[6], C3 = b4p[7];
    float Bv[NS] = {B0.x,B0.y,B0.z,B0.w, B1.x,B1.y,B1.z,B1.w,
                    B2.x,B2.y,B2.z,B2.w, B3.x,B3.y,B3.z,B3.w};
    float Cv[NS] = {C0.x,C0.y,C0.z,C0.w, C1.x,C1.y,C1.z,C1.w,
                    C2.x,C2.y,C2.z,C2.w, C3.x,C3.y,C3.z,C3.w};
    if (chain) {
      float ep[NS];
      pow_tree(__expf(a0 * dv), ep);
      #pragma unroll
      for (int n = 0; n < NS; ++n) h[n] = fmaf(ep[n], h[n], du*Bv[n]);
    } else {
      #pragma unroll
      for (int n = 0; n < NS; ++n) h[n] = fmaf(__expf(an[n]*dv), h[n], du*Bv[n]);
    }
    float p0 = Dd*u, p1 = 0.f, p2 = 0.f, p3 = 0.f;
    #pragma unroll
    for (int n = 0; n < NS; n += 4) {
      p0 = fmaf(h[n+0], Cv[n+0], p0);
      p1 = fmaf(h[n+1], Cv[n+1], p1);
      p2 = fmaf(h[n+2], Cv[n+2], p2);
      p3 = fmaf(h[n+3], Cv[n+3], p3);
    }
    int pos = odd ? (((l & 63) << 6) | (l >> 6)) : l;
    unsafeAtomicAdd(&ytot[((size_t)(b*LL) + pos)*DI + d], (p0+p1)+(p2+p3));
    l += dir; pu += pinc; pbc += bcinc;
  }
}

// ---------------- K5: LayerNorm + silu(z) gate + out_proj (32 rows/block)
__global__ __launch_bounds__(384) void k5_final(const float* __restrict__ ytot,
    const float* __restrict__ zs, const float* __restrict__ g,
    const float* __restrict__ bb, const float* __restrict__ ow,
    float* __restrict__ out)
{
  __shared__ float yt[32][DI+4];
  __shared__ float muS[32], rsS[32];
  int blk = blockIdx.x;
  int b = blk >> 7; int l0 = (blk & 127) << 5;
  int tid = threadIdx.x;
  for (int idx = tid; idx < 32*48; idx += 384) {
    int r = idx / 48, jj = idx % 48;
    ((float4*)yt[r])[jj] = *(const float4*)(ytot + ((size_t)(b*LL) + l0 + r)*DI + 4*jj);
  }
  __syncthreads();
  if (tid < 256) {
    int r = tid >> 3, q = tid & 7;
    const float* row = yt[r];
    float s1 = 0.f, s2 = 0.f;
    #pragma unroll
    for (int i = 0; i < 24; ++i) {
      float v = row[q*24 + i];
      s1 += v; s2 += v*v;
    }
    s1 += __shfl_xor(s1, 1); s2 += __shfl_xor(s2, 1);
    s1 += __shfl_xor(s1, 2); s2 += __shfl_xor(s2, 2);
    s1 += __shfl_xor(s1, 4); s2 += __shfl_xor(s2, 4);
    if (q == 0) {
      float mu = s1 / (float)DI;
      float var = s2 / (float)DI - mu*mu;
      muS[r] = mu;
      rsS[r] = rsqrtf(var + 1e-5f);
    }
  }
  __syncthreads();
  for (int idx = tid; idx < 32*48; idx += 384) {
    int r = idx / 48, jj = idx % 48;
    float4 y = ((float4*)yt[r])[jj];
    float mu = muS[r], rs = rsS[r];
    float4 g4 = *(const float4*)(g + 4*jj);
    float4 b4 = *(const float4*)(bb + 4*jj);
    float4 z4 = *(const float4*)(zs + ((size_t)(b*LL) + l0 + r)*DI + 4*jj);
    float4 v;
    v.x = fmaf((y.x-mu)*rs, g4.x, b4.x) * z4.x;
    v.y = fmaf((y.y-mu)*rs, g4.y, b4.y) * z4.y;
    v.z = fmaf((y.z-mu)*rs, g4.z, b4.z) * z4.z;
    v.w = fmaf((y.w-mu)*rs, g4.w, b4.w) * z4.w;
    ((float4*)yt[r])[jj] = v;
  }
  __syncthreads();
  {
    int c = tid % 96;
    int rg = tid / 96;
    const float4* wrow = (const float4*)(ow + (size_t)c*DI);
    float4 acc[8];
    #pragma unroll
    for (int rr = 0; rr < 8; ++rr) acc[rr] = make_float4(0.f,0.f,0.f,0.f);
    #pragma unroll
    for (int ch = 0; ch < 6; ++ch) {
      float4 wreg[8];
      #pragma unroll
      for (int jj = 0; jj < 8; ++jj) wreg[jj] = wrow[ch*8 + jj];
      #pragma unroll
      for (int rr = 0; rr < 8; ++rr) {
        const float4* yr = (const float4*)yt[rg*8 + rr];
        #pragma unroll
        for (int jj = 0; jj < 8; ++jj) fma4(acc[rr], wreg[jj], yr[ch*8 + jj]);
      }
    }
    #pragma unroll
    for (int rr = 0; rr < 8; ++rr) {
      float v = (acc[rr].x+acc[rr].y)+(acc[rr].z+acc[rr].w);
      out[((size_t)(b*LL) + l0 + rg*8 + rr)*DM + c] = v;
    }
  }
}

extern "C" void kernel_launch(void* const* d_in, const int* in_sizes, int n_in,
                              void* d_out, int out_size, void* d_ws, size_t ws_size,
                              hipStream_t stream)
{
  const float* x    = (const float*)d_in[0];
  const float* ipw  = (const float*)d_in[1];
  const float* cw   = (const float*)d_in[2];
  const float* cb   = (const float*)d_in[3];
  const float* xpw  = (const float*)d_in[4];
  const float* dtwp = (const float*)d_in[5];
  const float* dtbp = (const float*)d_in[6];
  const float* alog = (const float*)d_in[7];
  const float* dsp  = (const float*)d_in[8];
  const float* ng   = (const float*)d_in[9];
  const float* nbp  = (const float*)d_in[10];
  const float* owp  = (const float*)d_in[11];
  float* out = (float*)d_out;

  float* ws = (float*)d_ws;
  size_t off = 0;
  float* ytot = ws + off; off += (size_t)BN*LL*DI;
  float* zs   = ws + off; off += (size_t)BN*LL*DI;
  float* xi   = ws + off; off += (size_t)BN*LL*DI;
  float* U0   = ws + off; off += (size_t)BN*LL*DI;
  float* U1   = ws + off; off += (size_t)BN*LL*DI;
  float* BC   = ws + off; off += (size_t)BN*KK*LL*BCW;
  float* hst  = ws + off; off += (size_t)BN*KK*NCH*DI*NS;
  float* Ssum = ws + off; off += (size_t)BN*KK*NCH*DI;
  (void)ws_size; (void)in_sizes; (void)n_in; (void)out_size;

  hipMemsetAsync(ytot, 0, (size_t)BN*LL*DI*sizeof(float), stream);
  k1_inproj<<<dim3(BN*256), dim3(384), 0, stream>>>(x, ipw, xi, zs);
  k2_conv<<<dim3((BN*LL*48 + 255)/256), dim3(256), 0, stream>>>(xi, cw, cb, U0, U1);
  k3_xproj<<<dim3(BN*KK*128), dim3(320), 0, stream>>>(U0, U1, xpw, BC);
  k4a_pass1<<<dim3(BN*KK*NCH), dim3(192), 0, stream>>>(U0, U1, BC, alog, dtwp, dtbp, hst, Ssum);
  k4b_combine<<<dim3(BN*KK*12), dim3(256), 0, stream>>>(hst, Ssum, alog);
  k4c_pass2<<<dim3(BN*KK*NCH), dim3(192), 0, stream>>>(U0, U1, BC, alog, dtwp, dtbp, dsp, hst, ytot);
  k5_final<<<dim3(BN*128), dim3(384), 0, stream>>>(ytot, zs, ng, nbp, owp, out);
}